// Round 4
// baseline (57.756 us; speedup 1.0000x reference)
//
#include <hip/hip_runtime.h>

#define NBINS 256
#define EPSF 1e-12f

typedef float v4f __attribute__((ext_vector_type(4)));

// Fused: one 1024-thread block per (n,c) slice. Wave w (0..15) owns tile
// (bh=w>>2, bw=w&3): loads it, builds a wave-private LDS histogram, computes
// its Shannon entropy into ent_s[w]; after one barrier all waves bilinearly
// upsample the 4x4 entropy map to 256x256 straight from LDS.
__global__ __launch_bounds__(1024) void fused_entropy_kernel(const float* __restrict__ x,
                                                             float* __restrict__ out) {
    const int nc   = blockIdx.x;          // 0..511
    const int t    = threadIdx.x;
    const int lane = t & 63;
    const int wave = t >> 6;              // tile id

    __shared__ unsigned int hist[16][NBINS];   // 16 KB, wave-private
    __shared__ float ent_s[16];

    const float* tbase = x + ((size_t)nc << 16)
                           + (size_t)(wave >> 2) * (64 * 256)
                           + (size_t)(wave & 3) * 64;

    // ---- load 64 elems/lane (whole tile per wave), wave min/max ----
    v4f v[16];
    float lmin = INFINITY, lmax = -INFINITY;
#pragma unroll
    for (int k = 0; k < 16; ++k) {
        const int f   = lane + (k << 6);  // float4 index in tile, 0..1023
        const int row = f >> 4;           // 64 rows x 16 float4
        const int c4  = f & 15;
        v[k] = __builtin_nontemporal_load(
                   reinterpret_cast<const v4f*>(tbase + (size_t)row * 256 + c4 * 4));
        lmin = fminf(lmin, fminf(fminf(v[k].x, v[k].y), fminf(v[k].z, v[k].w)));
        lmax = fmaxf(lmax, fmaxf(fmaxf(v[k].x, v[k].y), fmaxf(v[k].z, v[k].w)));
    }
#pragma unroll
    for (int off = 32; off > 0; off >>= 1) {
        lmin = fminf(lmin, __shfl_xor(lmin, off));
        lmax = fmaxf(lmax, __shfl_xor(lmax, off));
    }

    // zero this wave's histogram (4 bins/lane as one uint4 store)
    {
        uint4 z; z.x = z.y = z.z = z.w = 0u;
        reinterpret_cast<uint4*>(hist[wave])[lane] = z;
    }
    __syncthreads();   // ordering: zero-stores before atomics (paranoia-cheap)

    const float width = (lmax - lmin) * (1.0f / NBINS);
    const float wsafe = (width > 0.0f) ? width : 1.0f;
    const float inv   = 1.0f / wsafe;     // one IEEE div; recip-mul binning

    unsigned int* h = hist[wave];
#pragma unroll
    for (int k = 0; k < 16; ++k) {
        float vals[4] = {v[k].x, v[k].y, v[k].z, v[k].w};
#pragma unroll
        for (int j = 0; j < 4; ++j) {
            float f   = floorf((vals[j] - lmin) * inv);
            int   bin = (int)fminf(fmaxf(f, 0.0f), 255.0f);
            atomicAdd(&h[bin], 1u);
        }
    }
    __syncthreads();

    // ---- entropy: 4 bins/lane ----
    {
        const uint4 c   = reinterpret_cast<const uint4*>(hist[wave])[lane];
        const float den = 4096.0f * wsafe;
        const float p0 = (float)c.x / den + EPSF;   // IEEE div per reference
        const float p1 = (float)c.y / den + EPSF;
        const float p2 = (float)c.z / den + EPSF;
        const float p3 = (float)c.w / den + EPSF;
        float s = p0 + p1 + p2 + p3;
#pragma unroll
        for (int off = 32; off > 0; off >>= 1) s += __shfl_xor(s, off);
        const float itot = 1.0f / s;      // pn = p/tot
        const float q0 = p0 * itot, q1 = p1 * itot, q2 = p2 * itot, q3 = p3 * itot;
        float e = q0 * log2f(q0) + q1 * log2f(q1) + q2 * log2f(q2) + q3 * log2f(q3);
#pragma unroll
        for (int off = 32; off > 0; off >>= 1) e += __shfl_xor(e, off);
        if (lane == 0) ent_s[wave] = -e;
    }
    __syncthreads();

    // ---- upsample 4x4 -> 256x256 from LDS ----
    // thread -> (x4 = t&63, base row yy = wave); iterates y = yy + 16*it.
    const int x4 = t & 63;
    const int yy = wave;

    // horizontal weights hoisted: ix uniform over this lane's 4 pixels
    // (boundaries 32/96/160/224 are multiples of 4)
    const int ix = (int)floorf(((x4 << 2) + 0.5f) * 0.015625f - 0.5f);
    const int x0 = max(ix, 0), x1 = min(ix + 1, 3);
    v4f wv[4];
#pragma unroll
    for (int j = 0; j < 4; ++j) {
        const float fx = ((x4 << 2) + j + 0.5f) * 0.015625f - 0.5f;
        const float wx = fx - floorf(fx);
        const float a  = 1.0f - wx, bb = wx;
        wv[j].x = ((x0 == 0) ? a : 0.0f) + ((x1 == 0) ? bb : 0.0f);
        wv[j].y = ((x0 == 1) ? a : 0.0f) + ((x1 == 1) ? bb : 0.0f);
        wv[j].z = ((x0 == 2) ? a : 0.0f) + ((x1 == 2) ? bb : 0.0f);
        wv[j].w = ((x0 == 3) ? a : 0.0f) + ((x1 == 3) ? bb : 0.0f);
    }

    const v4f* er = reinterpret_cast<const v4f*>(ent_s);   // 4 rows of 4
    v4f* out4 = reinterpret_cast<v4f*>(out) + ((size_t)nc << 14);
#pragma unroll
    for (int it = 0; it < 16; ++it) {
        const int   y   = yy + (it << 4);
        const float fy  = (y + 0.5f) * 0.015625f - 0.5f;
        const float fiy = floorf(fy);
        const float wy  = fy - fiy;
        const int   iy  = (int)fiy;
        const int   y0  = max(iy, 0), y1 = min(iy + 1, 3);
        const float wy0 = 1.0f - wy;

        const v4f r0 = er[y0];            // LDS broadcast (uniform per wave)
        const v4f r1 = er[y1];
        v4f rv = r0 * wy0 + r1 * wy;
        v4f o;
        o.x = rv.x * wv[0].x + rv.y * wv[0].y + rv.z * wv[0].z + rv.w * wv[0].w;
        o.y = rv.x * wv[1].x + rv.y * wv[1].y + rv.z * wv[1].z + rv.w * wv[1].w;
        o.z = rv.x * wv[2].x + rv.y * wv[2].y + rv.z * wv[2].z + rv.w * wv[2].w;
        o.w = rv.x * wv[3].x + rv.y * wv[3].y + rv.z * wv[3].z + rv.w * wv[3].w;
        __builtin_nontemporal_store(o, out4 + (y << 6) + x4);
    }
}

extern "C" void kernel_launch(void* const* d_in, const int* in_sizes, int n_in,
                              void* d_out, int out_size, void* d_ws, size_t ws_size,
                              hipStream_t stream) {
    const float* x   = (const float*)d_in[0];
    float*       out = (float*)d_out;
    fused_entropy_kernel<<<512, 1024, 0, stream>>>(x, out);
}

// Round 5
// 49.352 us; speedup vs baseline: 1.1703x; 1.1703x over previous
//
#include <hip/hip_runtime.h>

#define NBINS 256
#define EPSF 1e-12f

typedef float v4f __attribute__((ext_vector_type(4)));

// Wave-per-tile entropy: 2048 blocks x 256 threads; wave w owns tile
// blockIdx.x*4+w. Fully wave-local (shuffle reductions, wave-private LDS
// histogram) -> ZERO __syncthreads; waves never wait on each other.
__global__ __launch_bounds__(256) void entropy_kernel(const float* __restrict__ x,
                                                      float* __restrict__ ent) {
    const int lane = threadIdx.x & 63;
    const int wave = threadIdx.x >> 6;
    const int tile = (blockIdx.x << 2) + wave;    // 0..8191
    const int nc   = tile >> 4;
    const int th   = (tile >> 2) & 3;
    const int tw   = tile & 3;

    __shared__ unsigned int hist[4][NBINS];       // 4 KB, wave-private

    const float* tbase = x + ((size_t)nc << 16) + (size_t)th * (64 * 256) + (size_t)tw * 64;

    // ---- load whole tile: 16 float4/lane (nontemporal), wave min/max ----
    v4f v[16];
    float lmin = INFINITY, lmax = -INFINITY;
#pragma unroll
    for (int k = 0; k < 16; ++k) {
        const int f   = lane + (k << 6);          // float4 index 0..1023
        const int row = f >> 4;                   // 64 rows x 16 float4
        const int c4  = f & 15;
        v[k] = __builtin_nontemporal_load(
                   reinterpret_cast<const v4f*>(tbase + (size_t)row * 256 + c4 * 4));
        lmin = fminf(lmin, fminf(fminf(v[k].x, v[k].y), fminf(v[k].z, v[k].w)));
        lmax = fmaxf(lmax, fmaxf(fmaxf(v[k].x, v[k].y), fmaxf(v[k].z, v[k].w)));
    }
#pragma unroll
    for (int off = 32; off > 0; off >>= 1) {
        lmin = fminf(lmin, __shfl_xor(lmin, off));
        lmax = fmaxf(lmax, __shfl_xor(lmax, off));
    }

    // zero this wave's histogram (4 bins/lane, one uint4 store);
    // same-wave DS ops are processed in order -> no barrier needed
    uint4 z; z.x = z.y = z.z = z.w = 0u;
    reinterpret_cast<uint4*>(hist[wave])[lane] = z;

    const float width = (lmax - lmin) * (1.0f / NBINS);
    const float wsafe = (width > 0.0f) ? width : 1.0f;
    const float inv   = 1.0f / wsafe;             // one IEEE div; recip-mul binning

    unsigned int* h = hist[wave];
#pragma unroll
    for (int k = 0; k < 16; ++k) {
        float vals[4] = {v[k].x, v[k].y, v[k].z, v[k].w};
#pragma unroll
        for (int j = 0; j < 4; ++j) {
            float f   = floorf((vals[j] - lmin) * inv);
            int   bin = (int)fminf(fmaxf(f, 0.0f), 255.0f);
            atomicAdd(&h[bin], 1u);
        }
    }

    // ---- entropy: 4 bins/lane, wave-local shuffle sums ----
    const uint4 c   = reinterpret_cast<const uint4*>(hist[wave])[lane];
    const float den = 4096.0f * wsafe;
    const float p0 = (float)c.x / den + EPSF;     // IEEE div per reference
    const float p1 = (float)c.y / den + EPSF;
    const float p2 = (float)c.z / den + EPSF;
    const float p3 = (float)c.w / den + EPSF;
    float s = p0 + p1 + p2 + p3;
#pragma unroll
    for (int off = 32; off > 0; off >>= 1) s += __shfl_xor(s, off);
    const float itot = 1.0f / s;
    const float q0 = p0 * itot, q1 = p1 * itot, q2 = p2 * itot, q3 = p3 * itot;
    float e = q0 * log2f(q0) + q1 * log2f(q1) + q2 * log2f(q2) + q3 * log2f(q3);
#pragma unroll
    for (int off = 32; off > 0; off >>= 1) e += __shfl_xor(e, off);
    if (lane == 0) ent[tile] = -e;
}

// Half-pixel bilinear upsample (4x4 -> 256x256 per nc). Proven R3 form:
// tid -> (x4, y) fixed; unrolled loop walks nc only, all weight math hoisted.
__global__ __launch_bounds__(256) void upsample_kernel(const float* __restrict__ ent,
                                                       float* __restrict__ out) {
    const int tid = blockIdx.x * blockDim.x + threadIdx.x;   // 0..524287
    const int x4  = tid & 63;
    const int y   = (tid >> 6) & 255;
    const int nc0 = tid >> 14;                                // 0..31

    const float fy  = (y + 0.5f) * 0.015625f - 0.5f;
    const float fiy = floorf(fy);
    const float wy  = fy - fiy;
    const int   iy  = (int)fiy;
    const int   y0  = max(iy, 0), y1 = min(iy + 1, 3);
    const float wy0 = 1.0f - wy;

    const int ix = (int)floorf(((x4 << 2) + 0.5f) * 0.015625f - 0.5f);
    const int x0 = max(ix, 0), x1 = min(ix + 1, 3);

    v4f wv[4];
#pragma unroll
    for (int j = 0; j < 4; ++j) {
        const float fx = ((x4 << 2) + j + 0.5f) * 0.015625f - 0.5f;
        const float wx = fx - floorf(fx);
        const float a  = 1.0f - wx, bb = wx;
        wv[j].x = ((x0 == 0) ? a : 0.0f) + ((x1 == 0) ? bb : 0.0f);
        wv[j].y = ((x0 == 1) ? a : 0.0f) + ((x1 == 1) ? bb : 0.0f);
        wv[j].z = ((x0 == 2) ? a : 0.0f) + ((x1 == 2) ? bb : 0.0f);
        wv[j].w = ((x0 == 3) ? a : 0.0f) + ((x1 == 3) ? bb : 0.0f);
    }

    const v4f* e4 = reinterpret_cast<const v4f*>(ent);  // 4 v4f rows per nc
#pragma unroll
    for (int it = 0; it < 16; ++it) {
        const int nc = nc0 + (it << 5);
        const v4f r0 = e4[nc * 4 + y0];
        const v4f r1 = e4[nc * 4 + y1];
        v4f rv = r0 * wy0 + r1 * wy;
        v4f o;
        o.x = rv.x * wv[0].x + rv.y * wv[0].y + rv.z * wv[0].z + rv.w * wv[0].w;
        o.y = rv.x * wv[1].x + rv.y * wv[1].y + rv.z * wv[1].z + rv.w * wv[1].w;
        o.z = rv.x * wv[2].x + rv.y * wv[2].y + rv.z * wv[2].z + rv.w * wv[2].w;
        o.w = rv.x * wv[3].x + rv.y * wv[3].y + rv.z * wv[3].z + rv.w * wv[3].w;
        __builtin_nontemporal_store(o, reinterpret_cast<v4f*>(out) +
                                           ((size_t)nc << 14) + (y << 6) + x4);
    }
}

extern "C" void kernel_launch(void* const* d_in, const int* in_sizes, int n_in,
                              void* d_out, int out_size, void* d_ws, size_t ws_size,
                              hipStream_t stream) {
    const float* x   = (const float*)d_in[0];
    float*       out = (float*)d_out;
    float*       ent = (float*)d_ws;     // 8192 floats = 32 KB

    entropy_kernel<<<2048, 256, 0, stream>>>(x, ent);
    upsample_kernel<<<2048, 256, 0, stream>>>(ent, out);
}